// Round 3
// baseline (217.605 us; speedup 1.0000x reference)
//
#include <hip/hip_runtime.h>

// Problem constants (from reference setup_inputs)
constexpr int NA = 256;   // N_AGENTS
constexpr int B  = 64;    // BATCH
constexpr int S  = 20;    // SEQ
constexpr int H  = 128;   // HID

constexpr int AGENTS_PER_BLOCK = 16;  // 4 waves x 4 agents each
constexpr int BLOCKS = (NA / AGENTS_PER_BLOCK) * B;  // 16 * 64 = 1024

// One block per (batch b, group of 16 agents). 256 threads = 4 waves.
// Each wave owns 4 agents. R3 change vs R2: the gather loop is FUSED across
// the wave's 4 agents -- each round extracts one set bit from each of the 16
// wave-uniform mask words (4 agents x 4 words) and issues up to 16 independent
// coalesced 512B row loads before a single waitcnt, cutting exposed L2-hit
// round-trips per wave from ~16 to ~5. All gather control flow is scalar
// (masks live in SGPRs after __ballot).
// Numerics: distance bit-exact vs numpy fp32 -> __f*_rn, no FMA contraction,
// correctly-rounded sqrt, inclusive <=; __fdiv_rn epilogue.
__global__ __launch_bounds__(256, 4) void social_pool_kernel(
    const float* __restrict__ h,    // (NA, B, S, H)
    const float* __restrict__ p,    // (NA, B, S, 2)
    const float* __restrict__ rptr, // scalar radius
    float* __restrict__ out)        // (NA, B, H)
{
    const int group = blockIdx.x & (NA / AGENTS_PER_BLOCK - 1);  // 0..15
    const int b     = blockIdx.x >> 4;                           // 0..63
    const int tid   = threadIdx.x;
    const int wave  = tid >> 6;   // 0..3
    const int lane  = tid & 63;

    __shared__ float px[NA];
    __shared__ float py[NA];

    // Stage this batch's 256 last-timestep positions (scattered 8B loads).
    {
        const int j = tid;  // 256 threads, 256 agents
        const float2 pj = *(const float2*)(p + (((size_t)(j * B + b)) * S + (S - 1)) * 2);
        px[j] = pj.x;
        py[j] = pj.y;
    }
    __syncthreads();

    const float r = *rptr;
    const int ibase = group * AGENTS_PER_BLOCK + wave * 4;

    // Build neighbor bitmasks for all 4 agents: 16 wave-uniform 64-bit words.
    unsigned long long m[4][4];
    int n[4];
    #pragma unroll
    for (int a = 0; a < 4; ++a) {
        const int i = ibase + a;
        const float xi = px[i];
        const float yi = py[i];
        #pragma unroll
        for (int k = 0; k < 4; ++k) {
            const int j = (k << 6) + lane;
            const float dx   = __fsub_rn(xi, px[j]);
            const float dy   = __fsub_rn(yi, py[j]);
            const float d2   = __fadd_rn(__fmul_rn(dx, dx), __fmul_rn(dy, dy));
            const float dist = __fsqrt_rn(d2);
            m[a][k] = __ballot(dist <= r);
        }
        m[a][i >> 6] &= ~(1ull << (i & 63));  // exclude self
        n[a] = __popcll(m[a][0]) + __popcll(m[a][1]) + __popcll(m[a][2]) + __popcll(m[a][3]);
    }

    const size_t jstride = (size_t)B * S * H;
    const float* hb = h + ((size_t)b * S + (S - 1)) * H + 2 * lane;

    // Fused gather: one bit from each of the 16 words per round -> up to 16
    // independent loads in flight before the accumulate's waitcnt.
    float ax[4] = {0.f, 0.f, 0.f, 0.f};
    float ay[4] = {0.f, 0.f, 0.f, 0.f};
    bool any = (m[0][0] | m[0][1] | m[0][2] | m[0][3] |
                m[1][0] | m[1][1] | m[1][2] | m[1][3] |
                m[2][0] | m[2][1] | m[2][2] | m[2][3] |
                m[3][0] | m[3][1] | m[3][2] | m[3][3]) != 0ull;
    while (any) {
        float2 v[16];
        bool   got[16];
        #pragma unroll
        for (int w = 0; w < 16; ++w) {
            const int a = w >> 2, k = w & 3;
            got[w] = (m[a][k] != 0ull);
            if (got[w]) {
                const int j = (k << 6) + __builtin_ctzll(m[a][k]);
                m[a][k] &= m[a][k] - 1ull;
                v[w] = *(const float2*)(hb + (size_t)j * jstride);
            }
        }
        #pragma unroll
        for (int w = 0; w < 16; ++w) {
            const int a = w >> 2;
            if (got[w]) { ax[a] += v[w].x; ay[a] += v[w].y; }
        }
        any = (m[0][0] | m[0][1] | m[0][2] | m[0][3] |
               m[1][0] | m[1][1] | m[1][2] | m[1][3] |
               m[2][0] | m[2][1] | m[2][2] | m[2][3] |
               m[3][0] | m[3][1] | m[3][2] | m[3][3]) != 0ull;
    }

    #pragma unroll
    for (int a = 0; a < 4; ++a) {
        const int i = ibase + a;
        const float c = (float)(n[a] > 0 ? n[a] : 1);
        float2 o;
        o.x = __fdiv_rn(ax[a], c);
        o.y = __fdiv_rn(ay[a], c);
        *(float2*)(out + ((size_t)i * B + b) * H + 2 * lane) = o;
    }
}

extern "C" void kernel_launch(void* const* d_in, const int* in_sizes, int n_in,
                              void* d_out, int out_size, void* d_ws, size_t ws_size,
                              hipStream_t stream) {
    const float* h    = (const float*)d_in[0];
    const float* p    = (const float*)d_in[1];
    const float* rptr = (const float*)d_in[2];
    float* out        = (float*)d_out;

    (void)in_sizes; (void)n_in; (void)out_size; (void)d_ws; (void)ws_size;

    social_pool_kernel<<<dim3(BLOCKS), dim3(256), 0, stream>>>(h, p, rptr, out);
}